// Round 12
// baseline (7093.764 us; speedup 1.0000x reference)
//
#include <hip/hip_runtime.h>

typedef short s8v __attribute__((ext_vector_type(8)));
typedef float f4v __attribute__((ext_vector_type(4)));
typedef unsigned long long ull;

#define NLAYER 6
#define HID    512
#define PROJ   128
#define SEQT   512
#define BATCH  512
#define DSTEPS 32
#define TOTS   (SEQT + DSTEPS)   // 544
#define NG     2048              // 4*H
#define BC     64                // batch rows per unit
#define NCHUNK (BATCH / BC)      // 8
#define NUNIT  (NLAYER * NCHUNK) // 48
#define RINGP  4                 // partial-slab ring depth (steps)
#define PP_SH  8192              // one partial slab: [64 m][128 p] bf16
#define FSTRIDE 16               // tag padding: one tag per 64 B
#define TAGHALF (NUNIT * 4 * FSTRIDE)   // per-stream tag array span

// packed fragment counts (each fragment = 64 lanes * 16B = 1 KiB)
#define GFRAGS (NLAYER * 128 * 8 * 64)   // gates: [l][ntile=128][ktile=8][lane]
#define PFRAGS (NLAYER * 8 * 16 * 64)    // proj : [l][ntile=8][ktile=16][lane]
#define FFRAGS (8 * 4 * 64)              // fc   : [ntile=8][ktile=4][lane]
#define NFLAGS (2 * TAGHALF)             // tagA[48][4] ++ tagB[48][4], padded

static __device__ __forceinline__ unsigned short f2b(float f) {
    union { float f; unsigned int u; } v; v.f = f;
    unsigned int r = v.u + 0x7fffu + ((v.u >> 16) & 1u);  // RNE
    return (unsigned short)(r >> 16);
}
static __device__ __forceinline__ float b2f(unsigned short s) {
    union { float f; unsigned int u; } v; v.u = ((unsigned int)s) << 16;
    return v.f;
}
static __device__ __forceinline__ float sigf(float x) {
    x = fminf(fmaxf(x, -30.f), 30.f);
    return 1.f / (1.f + __expf(-x));
}
static __device__ __forceinline__ float tanh_fast(float x) {
    x = fminf(fmaxf(x, -15.f), 15.f);
    float t = __expf(-2.f * x);
    return (1.f - t) / (1.f + t);
}
static __device__ __forceinline__ f4v mfma16(s8v a, s8v b, f4v c) {
    return __builtin_amdgcn_mfma_f32_16x16x32_bf16(a, b, c, 0, 0, 0);
}
static __device__ __forceinline__ ull ald(const ull* p) {
    return __hip_atomic_load(p, __ATOMIC_RELAXED, __HIP_MEMORY_SCOPE_AGENT);
}
static __device__ __forceinline__ void spin_ge(unsigned* p, unsigned v) {
    while (__hip_atomic_load(p, __ATOMIC_RELAXED, __HIP_MEMORY_SCOPE_AGENT) < v)
        __builtin_amdgcn_s_sleep(2);
}
static __device__ __forceinline__ ull pk4(float a, float b, float c, float d) {
    return (ull)f2b(a) | ((ull)f2b(b) << 16) | ((ull)f2b(c) << 32) | ((ull)f2b(d) << 48);
}
static __device__ __forceinline__ float rsum4(ull v0, ull v1, ull v2, ull v3, int sh) {
    return b2f((unsigned short)(v0 >> sh)) + b2f((unsigned short)(v1 >> sh))
         + b2f((unsigned short)(v2 >> sh)) + b2f((unsigned short)(v3 >> sh));
}

// ---------------------------------------------------------------------------
// Prepack: fp32 weights -> bf16 MFMA B-fragment-linear layout, bias sum,
// zero sync tags. (identical fragment layout to rounds 1-11, which passed)
// ---------------------------------------------------------------------------
__global__ __launch_bounds__(256) void lstm_prepack(
    const float* __restrict__ Wih, const float* __restrict__ Whh,
    const float* __restrict__ bih, const float* __restrict__ bhh,
    const float* __restrict__ Whr, const float* __restrict__ Wfc,
    const float* __restrict__ bfcin,
    unsigned short* __restrict__ gB, unsigned short* __restrict__ pB,
    unsigned short* __restrict__ fB, float* __restrict__ bsum,
    float* __restrict__ bfc, unsigned int* __restrict__ flags)
{
    int tid = blockIdx.x * 256 + threadIdx.x;

    if (tid < GFRAGS) {  // gates: cat(Wih, Whh) over K=256
        const int lane = tid & 63;
        int rest = tid >> 6;
        const int kt = rest & 7;   rest >>= 3;
        const int nt = rest & 127; rest >>= 7;
        const int l  = rest;
        const int n  = nt * 16 + (lane & 15);
        const int kb = kt * 32 + (lane >> 4) * 8;
        const float* src = (kb < 128)
            ? (Wih + ((size_t)l * NG + n) * PROJ + kb)
            : (Whh + ((size_t)l * NG + n) * PROJ + (kb - 128));
        unsigned short o[8];
        #pragma unroll
        for (int e = 0; e < 8; ++e) o[e] = f2b(src[e]);
        *(s8v*)(gB + (size_t)tid * 8) = *(const s8v*)o;
        return;
    }
    tid -= GFRAGS;
    if (tid < PFRAGS) {  // proj: Whr (p x 512), frag[k][p] = Whr[p][k]
        const int lane = tid & 63;
        int rest = tid >> 6;
        const int kt = rest & 15; rest >>= 4;
        const int nt = rest & 7;  rest >>= 3;
        const int l  = rest;
        const int n  = nt * 16 + (lane & 15);
        const int kb = kt * 32 + (lane >> 4) * 8;
        const float* src = Whr + ((size_t)l * PROJ + n) * HID + kb;
        unsigned short o[8];
        #pragma unroll
        for (int e = 0; e < 8; ++e) o[e] = f2b(src[e]);
        *(s8v*)(pB + (size_t)tid * 8) = *(const s8v*)o;
        return;
    }
    tid -= PFRAGS;
    if (tid < FFRAGS) {  // fc: Wfc (128x128)
        const int lane = tid & 63;
        int rest = tid >> 6;
        const int kt = rest & 3;
        const int nt = rest >> 2;
        const int n  = nt * 16 + (lane & 15);
        const int kb = kt * 32 + (lane >> 4) * 8;
        const float* src = Wfc + (size_t)n * PROJ + kb;
        unsigned short o[8];
        #pragma unroll
        for (int e = 0; e < 8; ++e) o[e] = f2b(src[e]);
        *(s8v*)(fB + (size_t)tid * 8) = *(const s8v*)o;
        return;
    }
    tid -= FFRAGS;
    if (tid < NLAYER * NG) { bsum[tid] = bih[tid] + bhh[tid]; return; }
    tid -= NLAYER * NG;
    if (tid < PROJ) { bfc[tid] = bfcin[tid]; return; }
    tid -= PROJ;
    if (tid < NFLAGS) { flags[tid] = 0u; return; }
}

// ---------------------------------------------------------------------------
// Main: 192 blocks x 512 threads. Unit = (layer l, 64-row chunk): 4 sub-WGs.
// Gates weights persistent in 128 regs/wave; proj k-split, operand-swapped
// MFMA -> bf16 [64 m][128 p] partial slabs (ring depth 4); agent-scope
// relaxed tag stores after vmcnt-drain barriers (r11 protocol).
// vs r11: TWO-PHASE STREAM SPLIT. Rows 0-31 (stream A, mt 0/1) and rows
// 32-63 (stream B, mt 2/3) run as independent recurrences with per-stream
// tags: spinA|buildA|gatesA|projA|tagA then spinB|buildB|gatesB|projB|tagB.
// tagA(s) lands MID-step and is needed at spinA(s+1) -> phase B's work
// covers A's store-drain+visibility+discovery latency, and vice versa.
// r11's schedule had zero overlap (tag at end, spin at start).
// ---------------------------------------------------------------------------
__global__ __launch_bounds__(512) void lstm_main(
    const float* __restrict__ x,               // [512][512][128] fp32
    const unsigned short* __restrict__ gB,
    const unsigned short* __restrict__ pB,
    const unsigned short* __restrict__ fB,
    const float* __restrict__ bsum,            // [6][2048]
    const float* __restrict__ bfc,             // [128]
    unsigned int* __restrict__ flags,          // tagA ++ tagB
    unsigned short* __restrict__ pp,           // [48][4 slot][4 sub][8192] bf16
    float* __restrict__ out)                   // [512][32][128] fp32
{
    const int xcd  = blockIdx.x & 7;
    const int slot = blockIdx.x >> 3;      // 0..23
    const int uo   = slot >> 2;            // 0..5
    const int sub  = slot & 3;
    const int unit = xcd * 6 + uo;         // 0..47
    const int l    = unit >> 3;
    const int bb   = (unit & 7) * BC;

    __shared__ __align__(16) unsigned short xcat[64][264];    // A=[xt | h_rec], K=256
    __shared__ __align__(16) unsigned short hfullA[64][136];  // own j-quarter h_full
    __shared__ __align__(16) unsigned short pslab[2048 * 8];  // 32 KB proj W (k-slice)

    const int tid  = threadIdx.x;
    const int lane = tid & 63;
    const int w    = tid >> 6;            // wave 0..7
    const int u    = sub * 8 + w;         // unit-wave 0..31
    const int mrow = lane & 15;
    const int kgrp = lane >> 4;

    for (int i = tid; i < 64 * 264; i += 512) ((unsigned short*)xcat)[i] = 0;

    const s8v* gfrag = (const s8v*)gB;
    const s8v* pfrag = (const s8v*)pB;
    const s8v* ffrag = (const s8v*)fB;

    // ---- persistent gates weights: 32 fragments = 128 regs ----
    s8v wreg[4][8];
    #pragma unroll
    for (int g = 0; g < 4; ++g)
      #pragma unroll
      for (int kt = 0; kt < 8; ++kt)
        wreg[g][kt] = gfrag[(((size_t)l * 128 + g * 32 + u) * 8 + kt) * 64 + lane];

    float bias[4];
    #pragma unroll
    for (int g = 0; g < 4; ++g)
        bias[g] = bsum[l * NG + g * HID + u * 16 + mrow];

    // ---- proj W slab (own k-slice: all 128 p, k in [sub*128, sub*128+128)) ----
    for (int i = tid; i < 2048; i += 512) {
        const int nt = i >> 8, ktl = (i >> 6) & 3, ln = i & 63;
        ((s8v*)pslab)[i] = pfrag[(((size_t)l * 8 + nt) * 16 + sub * 4 + ktl) * 64 + ln];
    }

    f4v cst[4];
    #pragma unroll
    for (int mt = 0; mt < 4; ++mt) cst[mt] = (f4v){0.f, 0.f, 0.f, 0.f};

    unsigned int* tg = flags;   // tagA at +0, tagB at +TAGHALF

    __syncthreads();

    #pragma unroll 1
    for (int s = 0; s < TOTS; ++s) {
        #pragma unroll
        for (int ph = 0; ph < 2; ++ph) {
            unsigned int* tgP = tg + ph * TAGHALF;

            // ---- per-stream tag spins (parallel on waves 0/1/2) ----
            if (s > 0 && tid < 4)
                spin_ge(&tgP[(unit * 4 + tid) * FSTRIDE], (unsigned)s);          // own (s-1)
            if (l > 0 && tid >= 64 && tid < 68)
                spin_ge(&tgP[((unit - NCHUNK) * 4 + (tid - 64)) * FSTRIDE], (unsigned)(s + 1)); // upstream
            if (l < NLAYER - 1 && s >= RINGP && tid >= 128 && tid < 132)
                spin_ge(&tgP[((unit + NCHUNK) * 4 + (tid - 128)) * FSTRIDE], (unsigned)(s - RINGP + 1));
            __syncthreads();                                        // P-S1

            // ---- build xcat rows [ph*32, ph*32+32) ----
            if (l > 0) {
                const ull* bu = (const ull*)(pp + ((size_t)((unit - NCHUNK) * RINGP + (s & 3)) * 4) * PP_SH);
                const ull* bh = (const ull*)(pp + ((size_t)(unit * RINGP + ((s - 1) & 3)) * 4) * PP_SH);
                if (s > 0) {
                    #pragma unroll
                    for (int kk = 0; kk < 2; ++kk) {
                        const int idx = (ph * 2 + kk) * 512 + tid;   // ull idx in [64][128]
                        const int m = idx >> 5, p4 = idx & 31;
                        const ull a0 = ald(bu + idx),        a1 = ald(bu + 2048 + idx);
                        const ull a2 = ald(bu + 4096 + idx), a3 = ald(bu + 6144 + idx);
                        const ull b0 = ald(bh + idx),        b1 = ald(bh + 2048 + idx);
                        const ull b2 = ald(bh + 4096 + idx), b3 = ald(bh + 6144 + idx);
                        *(ull*)&xcat[m][p4 * 4] = pk4(
                            rsum4(a0, a1, a2, a3, 0),  rsum4(a0, a1, a2, a3, 16),
                            rsum4(a0, a1, a2, a3, 32), rsum4(a0, a1, a2, a3, 48));
                        *(ull*)&xcat[m][128 + p4 * 4] = pk4(
                            rsum4(b0, b1, b2, b3, 0),  rsum4(b0, b1, b2, b3, 16),
                            rsum4(b0, b1, b2, b3, 32), rsum4(b0, b1, b2, b3, 48));
                    }
                } else {
                    #pragma unroll
                    for (int kk = 0; kk < 2; ++kk) {
                        const int idx = (ph * 2 + kk) * 512 + tid;
                        const int m = idx >> 5, p4 = idx & 31;
                        const ull a0 = ald(bu + idx),        a1 = ald(bu + 2048 + idx);
                        const ull a2 = ald(bu + 4096 + idx), a3 = ald(bu + 6144 + idx);
                        *(ull*)&xcat[m][p4 * 4] = pk4(
                            rsum4(a0, a1, a2, a3, 0),  rsum4(a0, a1, a2, a3, 16),
                            rsum4(a0, a1, a2, a3, 32), rsum4(a0, a1, a2, a3, 48));
                    }
                }
            } else {
                if (s < SEQT) {
                    #pragma unroll
                    for (int kk = 0; kk < 2; ++kk) {
                        const int f = (ph * 2 + kk) * 512 + tid;     // float4 idx in [64][128]
                        const int m = f >> 5, q4 = f & 31;
                        const float4 v = *(const float4*)(x + (((size_t)(bb + m)) * SEQT + s) * PROJ + q4 * 4);
                        *(ull*)&xcat[m][q4 * 4] = pk4(v.x, v.y, v.z, v.w);
                    }
                } else if (s == SEQT) {
                    #pragma unroll
                    for (int kk = 0; kk < 2; ++kk) {
                        const int f = (ph * 2 + kk) * 512 + tid;
                        *(ull*)&xcat[f >> 5][(f & 31) * 4] = 0ull;
                    }
                }
                if (s > 0) {
                    const ull* bh = (const ull*)(pp + ((size_t)(unit * RINGP + ((s - 1) & 3)) * 4) * PP_SH);
                    #pragma unroll
                    for (int kk = 0; kk < 2; ++kk) {
                        const int idx = (ph * 2 + kk) * 512 + tid;
                        const int m = idx >> 5, p4 = idx & 31;
                        const ull b0 = ald(bh + idx),        b1 = ald(bh + 2048 + idx);
                        const ull b2 = ald(bh + 4096 + idx), b3 = ald(bh + 6144 + idx);
                        *(ull*)&xcat[m][128 + p4 * 4] = pk4(
                            rsum4(b0, b1, b2, b3, 0),  rsum4(b0, b1, b2, b3, 16),
                            rsum4(b0, b1, b2, b3, 32), rsum4(b0, b1, b2, b3, 48));
                    }
                }
            }
            __syncthreads();                                        // P-S2

            // ---- gates GEMM + pointwise for this stream's 2 m-tiles ----
            #pragma unroll
            for (int mm = 0; mm < 2; ++mm) {
                const int mt = ph * 2 + mm;
                f4v a0 = (f4v){bias[0], bias[0], bias[0], bias[0]};
                f4v a1 = (f4v){bias[1], bias[1], bias[1], bias[1]};
                f4v a2 = (f4v){bias[2], bias[2], bias[2], bias[2]};
                f4v a3 = (f4v){bias[3], bias[3], bias[3], bias[3]};
                #pragma unroll
                for (int kt = 0; kt < 8; ++kt) {
                    const s8v a = *(const s8v*)&xcat[mt * 16 + mrow][kt * 32 + kgrp * 8];
                    a0 = mfma16(a, wreg[0][kt], a0);
                    a1 = mfma16(a, wreg[1][kt], a1);
                    a2 = mfma16(a, wreg[2][kt], a2);
                    a3 = mfma16(a, wreg[3][kt], a3);
                }
                f4v cv = cst[mt];
                #pragma unroll
                for (int r = 0; r < 4; ++r) {
                    const float cn = sigf(a1[r]) * cv[r] + sigf(a0[r]) * tanh_fast(a2[r]);
                    const float hf = sigf(a3[r]) * tanh_fast(cn);
                    cv[r] = cn;
                    hfullA[mt * 16 + kgrp * 4 + r][w * 16 + mrow] = f2b(hf);
                }
                cst[mt] = cv;
            }
            __syncthreads();                                        // P-S3

            // ---- proj GEMM (k-split, operand-swapped), rows of this stream ----
            {
                f4v pacc[2];
                pacc[0] = (f4v){0.f, 0.f, 0.f, 0.f};
                pacc[1] = (f4v){0.f, 0.f, 0.f, 0.f};
                #pragma unroll
                for (int ktl = 0; ktl < 4; ++ktl) {
                    const s8v wf = ((const s8v*)pslab)[(w * 4 + ktl) * 64 + lane];
                    #pragma unroll
                    for (int mm = 0; mm < 2; ++mm) {
                        const int mt = ph * 2 + mm;
                        const s8v hf = *(const s8v*)&hfullA[mt * 16 + mrow][ktl * 32 + kgrp * 8];
                        pacc[mm] = mfma16(wf, hf, pacc[mm]);
                    }
                }
                unsigned short* dst = pp + ((size_t)(unit * RINGP + (s & 3)) * 4 + sub) * PP_SH;
                #pragma unroll
                for (int mm = 0; mm < 2; ++mm) {
                    const int mt = ph * 2 + mm;
                    ull* p8 = (ull*)(dst + (mt * 16 + mrow) * 128 + w * 16 + kgrp * 4);
                    __hip_atomic_store(p8, pk4(pacc[mm][0], pacc[mm][1], pacc[mm][2], pacc[mm][3]),
                                       __ATOMIC_RELAXED, __HIP_MEMORY_SCOPE_AGENT);
                }
            }
            __syncthreads();     // P-S4: drains this phase's data stores (vmcnt(0))
            if (tid == 0)
                __hip_atomic_store(&tgP[(unit * 4 + sub) * FSTRIDE], (unsigned)(s + 1),
                                   __ATOMIC_RELAXED, __HIP_MEMORY_SCOPE_AGENT);
        } // ph

        // ---- FC head (decode, last layer): needs both streams of step s ----
        if (l == NLAYER - 1 && s >= SEQT) {
            if (tid < 8) {
                unsigned int* tp = tg + (tid >> 2) * TAGHALF;
                spin_ge(&tp[(unit * 4 + (tid & 3)) * FSTRIDE], (unsigned)(s + 1));
            }
            __syncthreads();                                        // F-S1
            const ull* bh = (const ull*)(pp + ((size_t)(unit * RINGP + (s & 3)) * 4) * PP_SH);
            #pragma unroll
            for (int k = 0; k < 4; ++k) {
                const int idx = k * 512 + tid;
                const int m = idx >> 5, p4 = idx & 31;
                const ull b0 = ald(bh + idx),        b1 = ald(bh + 2048 + idx);
                const ull b2 = ald(bh + 4096 + idx), b3 = ald(bh + 6144 + idx);
                *(ull*)&hfullA[m][p4 * 4] = pk4(
                    sigf(rsum4(b0, b1, b2, b3, 0)),  sigf(rsum4(b0, b1, b2, b3, 16)),
                    sigf(rsum4(b0, b1, b2, b3, 32)), sigf(rsum4(b0, b1, b2, b3, 48)));
            }
            __syncthreads();                                        // F-S2
            const float bv = bfc[w * 16 + mrow];
            f4v facc[4];
            #pragma unroll
            for (int mt = 0; mt < 4; ++mt) facc[mt] = (f4v){bv, bv, bv, bv};
            #pragma unroll
            for (int kt = 0; kt < 4; ++kt) {
                const s8v bf = ffrag[((size_t)w * 4 + kt) * 64 + lane];
                #pragma unroll
                for (int mt = 0; mt < 4; ++mt) {
                    const s8v a = *(const s8v*)&hfullA[mt * 16 + mrow][kt * 32 + kgrp * 8];
                    facc[mt] = mfma16(a, bf, facc[mt]);
                }
            }
            const int td = s - SEQT;
            #pragma unroll
            for (int mt = 0; mt < 4; ++mt)
                #pragma unroll
                for (int r = 0; r < 4; ++r)
                    out[(((size_t)(bb + mt * 16 + kgrp * 4 + r)) * DSTEPS + td) * PROJ
                        + w * 16 + mrow] = facc[mt][r];
        }
    }
}

extern "C" void kernel_launch(void* const* d_in, const int* in_sizes, int n_in,
                              void* d_out, int out_size, void* d_ws, size_t ws_size,
                              hipStream_t stream)
{
    const float* x    = (const float*)d_in[0];
    const float* Wih  = (const float*)d_in[1];
    const float* Whh  = (const float*)d_in[2];
    const float* bih  = (const float*)d_in[3];
    const float* bhh  = (const float*)d_in[4];
    const float* Whr  = (const float*)d_in[5];
    const float* Wfc  = (const float*)d_in[6];
    const float* bfcv = (const float*)d_in[7];

    char* ws = (char*)d_ws;
    size_t off = 0;
    auto alloc = [&](size_t b) { char* p = ws + off; off += (b + 255) & ~(size_t)255; return p; };
    unsigned short* gB  = (unsigned short*)alloc((size_t)GFRAGS * 16);
    unsigned short* pB  = (unsigned short*)alloc((size_t)PFRAGS * 16);
    unsigned short* fB  = (unsigned short*)alloc((size_t)FFRAGS * 16);
    float* bsum         = (float*)alloc((size_t)NLAYER * NG * 4);
    float* bfc          = (float*)alloc((size_t)PROJ * 4);
    unsigned int* flags = (unsigned int*)alloc((size_t)NFLAGS * 4);
    unsigned short* pp  = (unsigned short*)alloc((size_t)NUNIT * RINGP * 4 * PP_SH * 2);
    if (off > ws_size) return;  // workspace too small; fail validation cleanly

    const int total = GFRAGS + PFRAGS + FFRAGS + NLAYER * NG + PROJ + NFLAGS;
    lstm_prepack<<<(total + 255) / 256, 256, 0, stream>>>(
        Wih, Whh, bih, bhh, Whr, Wfc, bfcv, gB, pB, fB, bsum, bfc, flags);
    lstm_main<<<NUNIT * 4, 512, 0, stream>>>(
        x, gB, pB, fB, bsum, bfc, flags, pp, (float*)d_out);
}

// Round 14
// 6955.779 us; speedup vs baseline: 1.0198x; 1.0198x over previous
//
#include <hip/hip_runtime.h>

typedef short s8v __attribute__((ext_vector_type(8)));
typedef float f4v __attribute__((ext_vector_type(4)));
typedef unsigned int u4v __attribute__((ext_vector_type(4)));
typedef unsigned long long ull;

#define NLAYER 6
#define HID    512
#define PROJ   128
#define SEQT   512
#define BATCH  512
#define DSTEPS 32
#define TOTS   (SEQT + DSTEPS)   // 544
#define NG     2048              // 4*H
#define BC     64                // batch rows per unit
#define NCHUNK (BATCH / BC)      // 8
#define NUNIT  (NLAYER * NCHUNK) // 48
#define RINGP  4                 // partial-slab ring depth (steps)
#define PP_SH  8192              // one partial slab: 16 KB bf16 (2048 ull)
#define FSTRIDE 16               // tag padding: one tag per 64 B

// packed fragment counts (each fragment = 64 lanes * 16B = 1 KiB)
#define GFRAGS (NLAYER * 128 * 8 * 64)   // gates: [l][ntile=128][ktile=8][lane]
#define PFRAGS (NLAYER * 8 * 16 * 64)    // proj : [l][ntile=8][ktile=16][lane]
#define FFRAGS (8 * 4 * 64)              // fc   : [ntile=8][ktile=4][lane]
#define NFLAGS (NUNIT * 4 * FSTRIDE)     // tag[unit][sub], padded

static __device__ __forceinline__ unsigned short f2b(float f) {
    union { float f; unsigned int u; } v; v.f = f;
    unsigned int r = v.u + 0x7fffu + ((v.u >> 16) & 1u);  // RNE
    return (unsigned short)(r >> 16);
}
static __device__ __forceinline__ float blo(unsigned int u) {
    union { unsigned int x; float f; } v; v.x = u << 16; return v.f;
}
static __device__ __forceinline__ float bhi(unsigned int u) {
    union { unsigned int x; float f; } v; v.x = u & 0xffff0000u; return v.f;
}
static __device__ __forceinline__ float sigf(float x) {
    x = fminf(fmaxf(x, -30.f), 30.f);
    return 1.f / (1.f + __expf(-x));
}
static __device__ __forceinline__ float tanh_fast(float x) {
    x = fminf(fmaxf(x, -15.f), 15.f);
    float t = __expf(-2.f * x);
    return (1.f - t) / (1.f + t);
}
static __device__ __forceinline__ f4v mfma16(s8v a, s8v b, f4v c) {
    return __builtin_amdgcn_mfma_f32_16x16x32_bf16(a, b, c, 0, 0, 0);
}
static __device__ __forceinline__ void spin_ge(unsigned* p, unsigned v) {
    while (__hip_atomic_load(p, __ATOMIC_RELAXED, __HIP_MEMORY_SCOPE_AGENT) < v)
        __builtin_amdgcn_s_sleep(2);
}
static __device__ __forceinline__ ull pk4(float a, float b, float c, float d) {
    return (ull)f2b(a) | ((ull)f2b(b) << 16) | ((ull)f2b(c) << 32) | ((ull)f2b(d) << 48);
}
static __device__ __forceinline__ ull red4(unsigned a0, unsigned a1, unsigned a2, unsigned a3,
                                           unsigned b0, unsigned b1, unsigned b2, unsigned b3) {
    return pk4(blo(a0) + blo(a1) + blo(a2) + blo(a3),
               bhi(a0) + bhi(a1) + bhi(a2) + bhi(a3),
               blo(b0) + blo(b1) + blo(b2) + blo(b3),
               bhi(b0) + bhi(b1) + bhi(b2) + bhi(b3));
}
static __device__ __forceinline__ ull red4s(unsigned a0, unsigned a1, unsigned a2, unsigned a3,
                                            unsigned b0, unsigned b1, unsigned b2, unsigned b3) {
    return pk4(sigf(blo(a0) + blo(a1) + blo(a2) + blo(a3)),
               sigf(bhi(a0) + bhi(a1) + bhi(a2) + bhi(a3)),
               sigf(blo(b0) + blo(b1) + blo(b2) + blo(b3)),
               sigf(bhi(b0) + bhi(b1) + bhi(b2) + bhi(b3)));
}
static __device__ __forceinline__ u4v mk4(ull a, ull b) {
    u4v r; r.x = (unsigned)a; r.y = (unsigned)(a >> 32);
    r.z = (unsigned)b; r.w = (unsigned)(b >> 32); return r;
}

// ---- 16B device-coherent (sc0 sc1) primitives: halve L3 transaction count ----
// 8 dwordx4 loads from the 4 sub-slabs of one slot (b pre-offset by tid*4 ull):
// r[2q] = sub q, mt{0,1}; r[2q+1] = sub q, mt{2,3}.
#define LD8_BODY(WAITSTR) \
    const ull* p0 = b;        const ull* p1 = b + 2;    \
    const ull* p2 = b + 2048; const ull* p3 = b + 2050; \
    const ull* p4 = b + 4096; const ull* p5 = b + 4098; \
    const ull* p6 = b + 6144; const ull* p7 = b + 6146; \
    asm volatile( \
        "global_load_dwordx4 %0, %8, off sc0 sc1\n\t"  \
        "global_load_dwordx4 %1, %9, off sc0 sc1\n\t"  \
        "global_load_dwordx4 %2, %10, off sc0 sc1\n\t" \
        "global_load_dwordx4 %3, %11, off sc0 sc1\n\t" \
        "global_load_dwordx4 %4, %12, off sc0 sc1\n\t" \
        "global_load_dwordx4 %5, %13, off sc0 sc1\n\t" \
        "global_load_dwordx4 %6, %14, off sc0 sc1\n\t" \
        "global_load_dwordx4 %7, %15, off sc0 sc1"     \
        WAITSTR \
        : "=&v"(r0), "=&v"(r1), "=&v"(r2), "=&v"(r3), \
          "=&v"(r4), "=&v"(r5), "=&v"(r6), "=&v"(r7)  \
        : "v"(p0), "v"(p1), "v"(p2), "v"(p3), "v"(p4), "v"(p5), "v"(p6), "v"(p7) \
        : "memory")

static __device__ __forceinline__ void ld8nw(const ull* b,
    u4v& r0, u4v& r1, u4v& r2, u4v& r3, u4v& r4, u4v& r5, u4v& r6, u4v& r7) {
    LD8_BODY("");
}
static __device__ __forceinline__ void ld8w8(const ull* b,
    u4v& r0, u4v& r1, u4v& r2, u4v& r3, u4v& r4, u4v& r5, u4v& r6, u4v& r7) {
    LD8_BODY("\n\ts_waitcnt vmcnt(8)");   // waits only the PREVIOUS 8-load batch
}
static __device__ __forceinline__ void ld8w0(const ull* b,
    u4v& r0, u4v& r1, u4v& r2, u4v& r3, u4v& r4, u4v& r5, u4v& r6, u4v& r7) {
    LD8_BODY("\n\ts_waitcnt vmcnt(0)");
}
// 32B store (2 x dwordx4) + ack wait (keeps the S4-barrier/tag ordering sound:
// the compiler's vmcnt bookkeeping cannot see asm stores).
static __device__ __forceinline__ void st16x2(ull* p, u4v v01, u4v v23) {
    asm volatile("global_store_dwordx4 %0, %2, off sc0 sc1\n\t"
                 "global_store_dwordx4 %1, %3, off sc0 sc1\n\t"
                 "s_waitcnt vmcnt(0)"
                 :: "v"(p), "v"(p + 2), "v"(v01), "v"(v23) : "memory");
}

// ---------------------------------------------------------------------------
// Prepack: fp32 weights -> bf16 MFMA fragment-linear layout, bias sum,
// zero sync tags. (identical fragment layout to rounds 1-12, which passed)
// ---------------------------------------------------------------------------
__global__ __launch_bounds__(256) void lstm_prepack(
    const float* __restrict__ Wih, const float* __restrict__ Whh,
    const float* __restrict__ bih, const float* __restrict__ bhh,
    const float* __restrict__ Whr, const float* __restrict__ Wfc,
    const float* __restrict__ bfcin,
    unsigned short* __restrict__ gB, unsigned short* __restrict__ pB,
    unsigned short* __restrict__ fB, float* __restrict__ bsum,
    float* __restrict__ bfc, unsigned int* __restrict__ flags)
{
    int tid = blockIdx.x * 256 + threadIdx.x;

    if (tid < GFRAGS) {  // gates: cat(Wih, Whh) over K=256
        const int lane = tid & 63;
        int rest = tid >> 6;
        const int kt = rest & 7;   rest >>= 3;
        const int nt = rest & 127; rest >>= 7;
        const int l  = rest;
        const int n  = nt * 16 + (lane & 15);
        const int kb = kt * 32 + (lane >> 4) * 8;
        const float* src = (kb < 128)
            ? (Wih + ((size_t)l * NG + n) * PROJ + kb)
            : (Whh + ((size_t)l * NG + n) * PROJ + (kb - 128));
        unsigned short o[8];
        #pragma unroll
        for (int e = 0; e < 8; ++e) o[e] = f2b(src[e]);
        *(s8v*)(gB + (size_t)tid * 8) = *(const s8v*)o;
        return;
    }
    tid -= GFRAGS;
    if (tid < PFRAGS) {  // proj: Whr (p x 512), frag[k][p] = Whr[p][k]
        const int lane = tid & 63;
        int rest = tid >> 6;
        const int kt = rest & 15; rest >>= 4;
        const int nt = rest & 7;  rest >>= 3;
        const int l  = rest;
        const int n  = nt * 16 + (lane & 15);
        const int kb = kt * 32 + (lane >> 4) * 8;
        const float* src = Whr + ((size_t)l * PROJ + n) * HID + kb;
        unsigned short o[8];
        #pragma unroll
        for (int e = 0; e < 8; ++e) o[e] = f2b(src[e]);
        *(s8v*)(pB + (size_t)tid * 8) = *(const s8v*)o;
        return;
    }
    tid -= PFRAGS;
    if (tid < FFRAGS) {  // fc: Wfc (128x128)
        const int lane = tid & 63;
        int rest = tid >> 6;
        const int kt = rest & 3;
        const int nt = rest >> 2;
        const int n  = nt * 16 + (lane & 15);
        const int kb = kt * 32 + (lane >> 4) * 8;
        const float* src = Wfc + (size_t)n * PROJ + kb;
        unsigned short o[8];
        #pragma unroll
        for (int e = 0; e < 8; ++e) o[e] = f2b(src[e]);
        *(s8v*)(fB + (size_t)tid * 8) = *(const s8v*)o;
        return;
    }
    tid -= FFRAGS;
    if (tid < NLAYER * NG) { bsum[tid] = bih[tid] + bhh[tid]; return; }
    tid -= NLAYER * NG;
    if (tid < PROJ) { bfc[tid] = bfcin[tid]; return; }
    tid -= PROJ;
    if (tid < NFLAGS) { flags[tid] = 0u; return; }
}

// ---------------------------------------------------------------------------
// Main: 192 blocks x 512 threads (r11 structure; last good = 7.09 ms).
// Unit = (layer l, 64-row chunk): 4 sub-WGs. Gates weights persistent in
// regs; proj k-split, operand-swapped MFMA; agent-scope tag protocol
// (relaxed store after store-ack, placement-independent).
// vs r11: 16-BYTE TRANSACTIONS. Partial slab re-laid out as ull index
// (mrow*32 + p_ull)*4 + mt so each lane's 4 mt-values are contiguous 32B:
// producer = 2 x global_store_dwordx4 sc0 sc1; consumers (one (mrow,p_ull)
// per thread) = 16 x dwordx4 loads instead of 32 x 8B atomics, issued as
// two 8-load batches with counted vmcnt(8)/vmcnt(0) + sched_barrier(0)
// fences -- the xt reduce overlaps the h_rec loads.
// ---------------------------------------------------------------------------
__global__ __launch_bounds__(512, 2) void lstm_main(
    const float* __restrict__ x,               // [512][512][128] fp32
    const unsigned short* __restrict__ gB,
    const unsigned short* __restrict__ pB,
    const unsigned short* __restrict__ fB,
    const float* __restrict__ bsum,            // [6][2048]
    const float* __restrict__ bfc,             // [128]
    unsigned int* __restrict__ flags,          // tag[48][4] padded x16
    unsigned short* __restrict__ pp,           // [48][4 slot][4 sub][8192] bf16
    float* __restrict__ out)                   // [512][32][128] fp32
{
    const int xcd  = blockIdx.x & 7;
    const int slot = blockIdx.x >> 3;      // 0..23
    const int uo   = slot >> 2;            // 0..5
    const int sub  = slot & 3;
    const int unit = xcd * 6 + uo;         // 0..47
    const int l    = unit >> 3;
    const int bb   = (unit & 7) * BC;

    __shared__ __align__(16) unsigned short xcat[64][264];    // A=[xt | h_rec], K=256
    __shared__ __align__(16) unsigned short hfullA[64][136];  // own j-quarter h_full
    __shared__ __align__(16) unsigned short pslab[2048 * 8];  // 32 KB proj W (k-slice)

    const int tid  = threadIdx.x;
    const int lane = tid & 63;
    const int w    = tid >> 6;            // wave 0..7
    const int u    = sub * 8 + w;         // unit-wave 0..31
    const int mrow = lane & 15;
    const int kgrp = lane >> 4;
    const int mrc  = tid >> 5;            // consumer mrow 0..15
    const int pc4  = (tid & 31) * 4;      // consumer p col (shorts)

    for (int i = tid; i < 64 * 264; i += 512) ((unsigned short*)xcat)[i] = 0;

    const s8v* gfrag = (const s8v*)gB;
    const s8v* pfrag = (const s8v*)pB;
    const s8v* ffrag = (const s8v*)fB;

    // ---- persistent gates weights: 32 fragments = 128 regs ----
    s8v wreg[4][8];
    #pragma unroll
    for (int g = 0; g < 4; ++g)
      #pragma unroll
      for (int kt = 0; kt < 8; ++kt)
        wreg[g][kt] = gfrag[(((size_t)l * 128 + g * 32 + u) * 8 + kt) * 64 + lane];

    float bias[4];
    #pragma unroll
    for (int g = 0; g < 4; ++g)
        bias[g] = bsum[l * NG + g * HID + u * 16 + mrow];

    // ---- proj W slab (own k-slice: all 128 p, k in [sub*128, sub*128+128)) ----
    for (int i = tid; i < 2048; i += 512) {
        const int nt = i >> 8, ktl = (i >> 6) & 3, ln = i & 63;
        ((s8v*)pslab)[i] = pfrag[(((size_t)l * 8 + nt) * 16 + sub * 4 + ktl) * 64 + ln];
    }

    f4v cst[4];
    #pragma unroll
    for (int mt = 0; mt < 4; ++mt) cst[mt] = (f4v){0.f, 0.f, 0.f, 0.f};

    unsigned int* tg = flags;   // tag[unit][sub] at (unit*4+sub)*FSTRIDE

    __syncthreads();

    #pragma unroll 1
    for (int s = 0; s < TOTS; ++s) {
        // ---- parallel tag spins: 4 lanes each of waves 0/1/2 (r11 protocol) ----
        if (s > 0 && tid < 4)
            spin_ge(&tg[(unit * 4 + tid) * FSTRIDE], (unsigned)s);              // own partials(s-1)
        if (l > 0 && tid >= 64 && tid < 68)
            spin_ge(&tg[((unit - NCHUNK) * 4 + (tid - 64)) * FSTRIDE], (unsigned)(s + 1)); // upstream(s)
        if (l < NLAYER - 1 && s >= RINGP && tid >= 128 && tid < 132)
            spin_ge(&tg[((unit + NCHUNK) * 4 + (tid - 128)) * FSTRIDE], (unsigned)(s - RINGP + 1)); // ring
        __syncthreads();                                            // S1

        // ---- build xcat (xt | h_rec), 16B-granule loads ----
        if (l > 0) {
            const ull* bu = (const ull*)(pp + ((size_t)((unit - NCHUNK) * RINGP + (s & 3)) * 4) * PP_SH) + tid * 4;
            if (s > 0) {
                const ull* bh = (const ull*)(pp + ((size_t)(unit * RINGP + ((s - 1) & 3)) * 4) * PP_SH) + tid * 4;
                u4v a0, a1, a2, a3, a4, a5, a6, a7, c0, c1, c2, c3, c4, c5, c6, c7;
                ld8nw(bu, a0, a1, a2, a3, a4, a5, a6, a7);          // xt batch (no wait)
                ld8w8(bh, c0, c1, c2, c3, c4, c5, c6, c7);          // h_rec batch; vmcnt(8) -> a* ready
                __builtin_amdgcn_sched_barrier(0);
                *(ull*)&xcat[     mrc][pc4] = red4(a0.x, a2.x, a4.x, a6.x, a0.y, a2.y, a4.y, a6.y);
                *(ull*)&xcat[16 + mrc][pc4] = red4(a0.z, a2.z, a4.z, a6.z, a0.w, a2.w, a4.w, a6.w);
                *(ull*)&xcat[32 + mrc][pc4] = red4(a1.x, a3.x, a5.x, a7.x, a1.y, a3.y, a5.y, a7.y);
                *(ull*)&xcat[48 + mrc][pc4] = red4(a1.z, a3.z, a5.z, a7.z, a1.w, a3.w, a5.w, a7.w);
                asm volatile("s_waitcnt vmcnt(0)" ::: "memory");    // c* ready
                __builtin_amdgcn_sched_barrier(0);
                *(ull*)&xcat[     mrc][128 + pc4] = red4(c0.x, c2.x, c4.x, c6.x, c0.y, c2.y, c4.y, c6.y);
                *(ull*)&xcat[16 + mrc][128 + pc4] = red4(c0.z, c2.z, c4.z, c6.z, c0.w, c2.w, c4.w, c6.w);
                *(ull*)&xcat[32 + mrc][128 + pc4] = red4(c1.x, c3.x, c5.x, c7.x, c1.y, c3.y, c5.y, c7.y);
                *(ull*)&xcat[48 + mrc][128 + pc4] = red4(c1.z, c3.z, c5.z, c7.z, c1.w, c3.w, c5.w, c7.w);
            } else {
                u4v a0, a1, a2, a3, a4, a5, a6, a7;
                ld8w0(bu, a0, a1, a2, a3, a4, a5, a6, a7);
                __builtin_amdgcn_sched_barrier(0);
                *(ull*)&xcat[     mrc][pc4] = red4(a0.x, a2.x, a4.x, a6.x, a0.y, a2.y, a4.y, a6.y);
                *(ull*)&xcat[16 + mrc][pc4] = red4(a0.z, a2.z, a4.z, a6.z, a0.w, a2.w, a4.w, a6.w);
                *(ull*)&xcat[32 + mrc][pc4] = red4(a1.x, a3.x, a5.x, a7.x, a1.y, a3.y, a5.y, a7.y);
                *(ull*)&xcat[48 + mrc][pc4] = red4(a1.z, a3.z, a5.z, a7.z, a1.w, a3.w, a5.w, a7.w);
            }
        } else {
            if (s < SEQT) {
                #pragma unroll
                for (int k = 0; k < 4; ++k) {
                    const int f = k * 512 + tid;                    // float4 idx in [64][128]
                    const int m = f >> 5, q4 = f & 31;
                    const float4 v = *(const float4*)(x + (((size_t)(bb + m)) * SEQT + s) * PROJ + q4 * 4);
                    *(ull*)&xcat[m][q4 * 4] = pk4(v.x, v.y, v.z, v.w);
                }
            } else if (s == SEQT) {
                #pragma unroll
                for (int k = 0; k < 4; ++k) {
                    const int f = k * 512 + tid;
                    *(ull*)&xcat[f >> 5][(f & 31) * 4] = 0ull;
                }
            }
            if (s > 0) {
                const ull* bh = (const ull*)(pp + ((size_t)(unit * RINGP + ((s - 1) & 3)) * 4) * PP_SH) + tid * 4;
                u4v c0, c1, c2, c3, c4, c5, c6, c7;
                ld8w0(bh, c0, c1, c2, c3, c4, c5, c6, c7);
                __builtin_amdgcn_sched_barrier(0);
                *(ull*)&xcat[     mrc][128 + pc4] = red4(c0.x, c2.x, c4.x, c6.x, c0.y, c2.y, c4.y, c6.y);
                *(ull*)&xcat[16 + mrc][128 + pc4] = red4(c0.z, c2.z, c4.z, c6.z, c0.w, c2.w, c4.w, c6.w);
                *(ull*)&xcat[32 + mrc][128 + pc4] = red4(c1.x, c3.x, c5.x, c7.x, c1.y, c3.y, c5.y, c7.y);
                *(ull*)&xcat[48 + mrc][128 + pc4] = red4(c1.z, c3.z, c5.z, c7.z, c1.w, c3.w, c5.w, c7.w);
            }
        }
        __syncthreads();                                            // S2

        // ---- gates GEMM (weights in regs) + pointwise, mt-outer ----
        #pragma unroll
        for (int mt = 0; mt < 4; ++mt) {
            f4v a0 = (f4v){bias[0], bias[0], bias[0], bias[0]};
            f4v a1 = (f4v){bias[1], bias[1], bias[1], bias[1]};
            f4v a2 = (f4v){bias[2], bias[2], bias[2], bias[2]};
            f4v a3 = (f4v){bias[3], bias[3], bias[3], bias[3]};
            #pragma unroll
            for (int kt = 0; kt < 8; ++kt) {
                const s8v a = *(const s8v*)&xcat[mt * 16 + mrow][kt * 32 + kgrp * 8];
                a0 = mfma16(a, wreg[0][kt], a0);
                a1 = mfma16(a, wreg[1][kt], a1);
                a2 = mfma16(a, wreg[2][kt], a2);
                a3 = mfma16(a, wreg[3][kt], a3);
            }
            f4v cv = cst[mt];
            #pragma unroll
            for (int r = 0; r < 4; ++r) {
                const float cn = sigf(a1[r]) * cv[r] + sigf(a0[r]) * tanh_fast(a2[r]);
                const float hf = sigf(a3[r]) * tanh_fast(cn);
                cv[r] = cn;
                hfullA[mt * 16 + kgrp * 4 + r][w * 16 + mrow] = f2b(hf);  // local j col
            }
            cst[mt] = cv;
        }
        __syncthreads();                                            // S3

        // ---- proj GEMM, K-SPLIT, OPERAND-SWAPPED: D[p-row][m-col] ----
        {
            f4v pacc[4];
            #pragma unroll
            for (int mt = 0; mt < 4; ++mt) pacc[mt] = (f4v){0.f, 0.f, 0.f, 0.f};
            #pragma unroll
            for (int ktl = 0; ktl < 4; ++ktl) {
                const s8v wf = ((const s8v*)pslab)[(w * 4 + ktl) * 64 + lane];  // A: p rows
                #pragma unroll
                for (int mt = 0; mt < 4; ++mt) {
                    const s8v hf = *(const s8v*)&hfullA[mt * 16 + mrow][ktl * 32 + kgrp * 8]; // B: m cols
                    pacc[mt] = mfma16(wf, hf, pacc[mt]);
                }
            }
            // lane holds p = w*16 + kgrp*4 + r (r=0..3), m = mt*16 + mrow.
            // slab layout: ull idx (mrow*32 + p_ull)*4 + mt  ->  32B contiguous/lane.
            ull* dst = (ull*)(pp + ((size_t)(unit * RINGP + (s & 3)) * 4 + sub) * PP_SH)
                       + ((size_t)mrow * 32 + w * 4 + kgrp) * 4;
            st16x2(dst,
                   mk4(pk4(pacc[0][0], pacc[0][1], pacc[0][2], pacc[0][3]),
                       pk4(pacc[1][0], pacc[1][1], pacc[1][2], pacc[1][3])),
                   mk4(pk4(pacc[2][0], pacc[2][1], pacc[2][2], pacc[2][3]),
                       pk4(pacc[3][0], pacc[3][1], pacc[3][2], pacc[3][3])));
        }
        __syncthreads();      // S4: all waves' stores ack'd (st16x2 ends vmcnt(0))
        if (tid == 0)         // tag AFTER the drain -> plain relaxed store
            __hip_atomic_store(&tg[(unit * 4 + sub) * FSTRIDE], (unsigned)(s + 1),
                               __ATOMIC_RELAXED, __HIP_MEMORY_SCOPE_AGENT);

        // ---- FC head (decode, last layer): reduce own partials(s), sigf, GEMM ----
        if (l == NLAYER - 1 && s >= SEQT) {
            if (tid < 4) spin_ge(&tg[(unit * 4 + tid) * FSTRIDE], (unsigned)(s + 1));
            __syncthreads();                                        // S5
            const ull* bh = (const ull*)(pp + ((size_t)(unit * RINGP + (s & 3)) * 4) * PP_SH) + tid * 4;
            u4v a0, a1, a2, a3, a4, a5, a6, a7;
            ld8w0(bh, a0, a1, a2, a3, a4, a5, a6, a7);
            __builtin_amdgcn_sched_barrier(0);
            *(ull*)&hfullA[     mrc][pc4] = red4s(a0.x, a2.x, a4.x, a6.x, a0.y, a2.y, a4.y, a6.y);
            *(ull*)&hfullA[16 + mrc][pc4] = red4s(a0.z, a2.z, a4.z, a6.z, a0.w, a2.w, a4.w, a6.w);
            *(ull*)&hfullA[32 + mrc][pc4] = red4s(a1.x, a3.x, a5.x, a7.x, a1.y, a3.y, a5.y, a7.y);
            *(ull*)&hfullA[48 + mrc][pc4] = red4s(a1.z, a3.z, a5.z, a7.z, a1.w, a3.w, a5.w, a7.w);
            __syncthreads();                                        // S6
            const float bv = bfc[w * 16 + mrow];
            f4v facc[4];
            #pragma unroll
            for (int mt = 0; mt < 4; ++mt) facc[mt] = (f4v){bv, bv, bv, bv};
            #pragma unroll
            for (int kt = 0; kt < 4; ++kt) {
                const s8v bf = ffrag[((size_t)w * 4 + kt) * 64 + lane];
                #pragma unroll
                for (int mt = 0; mt < 4; ++mt) {
                    const s8v a = *(const s8v*)&hfullA[mt * 16 + mrow][kt * 32 + kgrp * 8];
                    facc[mt] = mfma16(a, bf, facc[mt]);
                }
            }
            const int td = s - SEQT;
            #pragma unroll
            for (int mt = 0; mt < 4; ++mt)
                #pragma unroll
                for (int r = 0; r < 4; ++r)
                    out[(((size_t)(bb + mt * 16 + kgrp * 4 + r)) * DSTEPS + td) * PROJ
                        + w * 16 + mrow] = facc[mt][r];
        }
    }
}

extern "C" void kernel_launch(void* const* d_in, const int* in_sizes, int n_in,
                              void* d_out, int out_size, void* d_ws, size_t ws_size,
                              hipStream_t stream)
{
    const float* x    = (const float*)d_in[0];
    const float* Wih  = (const float*)d_in[1];
    const float* Whh  = (const float*)d_in[2];
    const float* bih  = (const float*)d_in[3];
    const float* bhh  = (const float*)d_in[4];
    const float* Whr  = (const float*)d_in[5];
    const float* Wfc  = (const float*)d_in[6];
    const float* bfcv = (const float*)d_in[7];

    char* ws = (char*)d_ws;
    size_t off = 0;
    auto alloc = [&](size_t b) { char* p = ws + off; off += (b + 255) & ~(size_t)255; return p; };
    unsigned short* gB  = (unsigned short*)alloc((size_t)GFRAGS * 16);
    unsigned short* pB  = (unsigned short*)alloc((size_t)PFRAGS * 16);
    unsigned short* fB  = (unsigned short*)alloc((size_t)FFRAGS * 16);
    float* bsum         = (float*)alloc((size_t)NLAYER * NG * 4);
    float* bfc          = (float*)alloc((size_t)PROJ * 4);
    unsigned int* flags = (unsigned int*)alloc((size_t)NFLAGS * 4);
    unsigned short* pp  = (unsigned short*)alloc((size_t)NUNIT * RINGP * 4 * PP_SH * 2);
    if (off > ws_size) return;  // workspace too small; fail validation cleanly

    const int total = GFRAGS + PFRAGS + FFRAGS + NLAYER * NG + PROJ + NFLAGS;
    lstm_prepack<<<(total + 255) / 256, 256, 0, stream>>>(
        Wih, Whh, bih, bhh, Whr, Wfc, bfcv, gB, pB, fB, bsum, bfc, flags);
    lstm_main<<<NUNIT * 4, 512, 0, stream>>>(
        x, gB, pB, fB, bsum, bfc, flags, pp, (float*)d_out);
}